// Round 14
// baseline (363.616 us; speedup 1.0000x reference)
//
#include <hip/hip_runtime.h>
#include <hip/hip_bf16.h>
#include <cstdint>
#include <cstddef>

// Problem: B=64, L=2048, E=1024, A=512
#define BB   64
#define LL   2048
#define ED   1024
#define AD   512
#define BM   64           // l-rows per block (block = 64 x 512, 4 waves of 64x64... 8N)
#define NCH  (LL / BM)    // 32 chunks per batch row
#define KST  32           // 32 K-steps of BK=32

typedef short  short4v __attribute__((ext_vector_type(4)));
typedef short  short8  __attribute__((ext_vector_type(8)));
typedef float  f32x4   __attribute__((ext_vector_type(4)));

__device__ __forceinline__ unsigned short f2bf(float x) {
  unsigned u = __float_as_uint(x);
  u += 0x7FFFu + ((u >> 16) & 1u);
  return (unsigned short)(u >> 16);
}

__device__ __forceinline__ short4v cvt4(f32x4 v) {
  union { short4v s; unsigned u[2]; } r;
  asm("v_cvt_pk_bf16_f32 %0, %1, %2" : "=v"(r.u[0]) : "v"(v[0]), "v"(v[1]));
  asm("v_cvt_pk_bf16_f32 %0, %1, %2" : "=v"(r.u[1]) : "v"(v[2]), "v"(v[3]));
  return r.s;
}

#define GLOAD_LDS16(gp, lp)                                                        \
  __builtin_amdgcn_global_load_lds(                                                \
      (const __attribute__((address_space(1))) unsigned int*)(gp),                 \
      (__attribute__((address_space(3))) unsigned int*)(lp), 16, 0, 0)

// ---------------- kernel 0: prep (REWORKED for parallel W_dec streaming) --------
// blocks 0..15   : dec_proj col-slice. Block g owns cols [g*32, g*32+32): reads its
//   128 KB W_dec slice ONCE (coalesced), dec staged via LDS in 32-KB chunks
//   (broadcast reads). Old version: 64 blocks x full 2 MB W_dec stream (~50 us).
// blocks 16..143 : pack W_enc fp32 -> bf16 in the fused kernel's LDS image order:
//   o = ks*16384 + cblk*512 + kg*128 + r*8 + j ; k = ks*32+kg*8+j, col = cblk*16+r
__global__ __launch_bounds__(512) void prep_kernel(
    const float* __restrict__ W_enc, const float* __restrict__ dec,
    const float* __restrict__ W_dec, const float* __restrict__ b_dec,
    unsigned short* __restrict__ Wb, float* __restrict__ dp) {
  const int blk = blockIdx.x, t = threadIdx.x;
  if (blk < 16) {
    __shared__ float ld[64][128];        // 32 KB dec chunk
    const int cl = t & 31;               // col within slice
    const int bg = t >> 5;               // 0..15 (group of 4 batches)
    const int c  = blk * 32 + cl;
    float a0 = 0.f, a1 = 0.f, a2 = 0.f, a3 = 0.f;
    for (int kc = 0; kc < 8; kc++) {
      __syncthreads();
#pragma unroll
      for (int j = 0; j < 16; j++) {
        const int idx = j * 512 + t;     // 0..8191
        ld[idx >> 7][idx & 127] = dec[(idx >> 7) * ED + kc * 128 + (idx & 127)];
      }
      __syncthreads();
#pragma unroll 4
      for (int kk = 0; kk < 128; kk++) {
        const float w = W_dec[(kc * 128 + kk) * AD + c];
        a0 = fmaf(ld[bg * 4 + 0][kk], w, a0);
        a1 = fmaf(ld[bg * 4 + 1][kk], w, a1);
        a2 = fmaf(ld[bg * 4 + 2][kk], w, a2);
        a3 = fmaf(ld[bg * 4 + 3][kk], w, a3);
      }
    }
    const float bd = b_dec[c];
    dp[(bg * 4 + 0) * AD + c] = a0 + bd;
    dp[(bg * 4 + 1) * AD + c] = a1 + bd;
    dp[(bg * 4 + 2) * AD + c] = a2 + bd;
    dp[(bg * 4 + 3) * AD + c] = a3 + bd;
  } else {
    const int base = (blk - 16) * 4096;
#pragma unroll
    for (int ii = 0; ii < 8; ii++) {
      const int o    = base + ii * 512 + t;
      const int ks   = o >> 14;
      const int cblk = (o >> 9) & 31;
      const int kg   = (o >> 7) & 3;
      const int r    = (o >> 3) & 15;
      const int j    = o & 7;
      const int k    = ks * 32 + kg * 8 + j;
      const int c    = cblk * 16 + r;
      Wb[o] = f2bf(W_enc[k * AD + c]);
    }
  }
}

// ---------------- kernel 1: fused (R4 best-measured structure + vmcnt(1) fix) ---
// grid (NCH=32, BB), 256 threads = 4 waves (1M x 4N... 8N? wave tile 64x128? no:
// 4 waves, each owns 128 cols? R4: wn = t>>6 in 0..3, wave tile 64 rows x 128 cols
// -> acc[4][8]? No: R4 used acc[4][8]. Replicated EXACTLY below (passed, 283.6us);
// only change: end-of-iter vmcnt(2) -> vmcnt(1) so all 8 B-DMAs drain before the
// barrier (ISA-level race in R4; passed by timing margin only).
__global__ __launch_bounds__(256, 2) void fused_kernel(
    const float* __restrict__ sem, const unsigned short* __restrict__ Wb,
    const float* __restrict__ dp, const float* __restrict__ b_enc,
    const float* __restrict__ Wf,
    float* __restrict__ raw_scores,
    float* __restrict__ ws_ms, float* __restrict__ ws_o) {

  __shared__ unsigned short Alds[2][2048];    // [buf][rblk(4)][kg(4)][16][8]   8 KB
  __shared__ unsigned short Blds[2][16384];   // [buf][cblk(32)][kg(4)][16][8] 64 KB

  const int t    = threadIdx.x;
  const int lane = t & 63;
  const int wn   = t >> 6;      // 0..3 col quarter (4 waves)
  const int b    = blockIdx.y;
  const int chunk= blockIdx.x;
  const int l0   = chunk * BM;

  const int srow = t >> 2;      // 0..63
  const int skg  = t & 3;       // 0..3
  const float* aptr = sem + ((size_t)(b * LL + l0 + srow)) * ED + skg * 8;
  const unsigned short* bsrc = Wb + t * 8;    // + ks*16384 + i*2048
  const int awr = (srow >> 4) * 512 + skg * 128 + (srow & 15) * 8;

  const int arow = lane & 15;
  const int akg  = lane >> 4;
  const int afr  = lane * 8;                  // + mf*512
  const int bfr  = wn * 4096 + lane * 8;      // + nf*512 (wave quarter = 128 cols)

  f32x4 acc[4][8];
#pragma unroll
  for (int i = 0; i < 4; i++)
#pragma unroll
    for (int j = 0; j < 8; j++) acc[i][j] = (f32x4)0.f;

  // ---- prologue ----
  {
    f32x4 f0 = *(const f32x4*)(aptr);
    f32x4 f1 = *(const f32x4*)(aptr + 4);
#pragma unroll
    for (int i = 0; i < 8; i++)
      GLOAD_LDS16(bsrc + i * 2048, &Blds[0][i * 2048 + t * 8]);
    __builtin_amdgcn_sched_barrier(0);
    short4v lo = cvt4(f0), hi = cvt4(f1);
    *(short4v*)&Alds[0][awr]     = lo;
    *(short4v*)&Alds[0][awr + 4] = hi;
  }
  asm volatile("s_waitcnt vmcnt(0) lgkmcnt(0)" ::: "memory");
  __builtin_amdgcn_sched_barrier(0);
  __builtin_amdgcn_s_barrier();

  // A reg-staged one step ahead: entering ITER(ks), (CA0,CA1) hold A(ks+1).
  f32x4 pA0, pA1, qA0, qA1;
  {
    const float* ap = aptr + 32;
    qA0 = *(const f32x4*)(ap);
    qA1 = *(const f32x4*)(ap + 4);
  }

#define ITER(ks, CA0, CA1, LA0, LA1)                                               \
  {                                                                                \
    const int cb = (ks) & 1, nb = ((ks) + 1) & 1;                                  \
    if ((ks) + 1 < KST) {                                                          \
      const unsigned short* bs = bsrc + ((ks) + 1) * 16384;                        \
      _Pragma("unroll")                                                            \
      for (int i = 0; i < 8; i++)                                                  \
        GLOAD_LDS16(bs + i * 2048, &Blds[nb][i * 2048 + t * 8]);                   \
    }                                                                              \
    __builtin_amdgcn_sched_barrier(0);  /* pin: B DMAs before A cvt/load */        \
    if ((ks) + 1 < KST) {                                                          \
      short4v lo = cvt4(CA0), hi = cvt4(CA1);                                      \
      *(short4v*)&Alds[nb][awr]     = lo;                                          \
      *(short4v*)&Alds[nb][awr + 4] = hi;                                          \
    }                                                                              \
    if ((ks) + 2 < KST) {                                                          \
      const float* ap = aptr + ((ks) + 2) * 32;                                    \
      LA0 = *(const f32x4*)(ap);                                                   \
      LA1 = *(const f32x4*)(ap + 4);                                               \
    }                                                                              \
    short8 av[4], bv[8];                                                           \
    _Pragma("unroll")                                                              \
    for (int mf = 0; mf < 4; mf++)                                                 \
      av[mf] = *(const short8*)&Alds[cb][afr + mf * 512];                          \
    _Pragma("unroll")                                                              \
    for (int nf = 0; nf < 8; nf++)                                                 \
      bv[nf] = *(const short8*)&Blds[cb][bfr + nf * 512];                          \
    __builtin_amdgcn_s_setprio(1);                                                 \
    _Pragma("unroll")                                                              \
    for (int mf = 0; mf < 4; mf++)                                                 \
      _Pragma("unroll")                                                            \
      for (int nf = 0; nf < 8; nf++)                                               \
        acc[mf][nf] = __builtin_amdgcn_mfma_f32_16x16x32_bf16(av[mf], bv[nf], acc[mf][nf], 0, 0, 0); \
    __builtin_amdgcn_s_setprio(0);                                                 \
    if ((ks) + 2 < KST) {  /* vmcnt(1): all 8 B-DMAs drained; only LA in flight */ \
      asm volatile("s_waitcnt vmcnt(1) lgkmcnt(0)" ::: "memory");                  \
    } else {                                                                       \
      asm volatile("s_waitcnt vmcnt(0) lgkmcnt(0)" ::: "memory");                  \
    }                                                                              \
    __builtin_amdgcn_sched_barrier(0);                                             \
    __builtin_amdgcn_s_barrier();                                                  \
  }

  for (int kk = 0; kk < KST; kk += 2) {
    ITER(kk,     qA0, qA1, pA0, pA1);
    ITER(kk + 1, pA0, pA1, qA0, qA1);
  }
#undef ITER

  // ---- epilogue smem carved out of Blds ----
  float* eb = (float*)&Blds[0][0];
  float (*sc_part)[4] = (float (*)[4])eb;     // 64 x 4
  float* weight       = eb + 256;             // 64

  float dpv[8], wfv[8], bev[8];
#pragma unroll
  for (int nf = 0; nf < 8; nf++) {
    const int c = wn * 128 + nf * 16 + arow;
    dpv[nf] = dp[b * AD + c];
    wfv[nf] = Wf[c];
    bev[nf] = b_enc[c];
  }
#pragma unroll
  for (int mf = 0; mf < 4; mf++) {
#pragma unroll
    for (int r = 0; r < 4; r++) {
      float p = 0.f;
#pragma unroll
      for (int nf = 0; nf < 8; nf++) {
        float e = acc[mf][nf][r] + bev[nf];
        acc[mf][nf][r] = e;                    // keep enc_proj (+b_enc) for o-accum
        float x = e + dpv[nf];
        float ex = __expf(2.f * x);            // tanh via exp
        float th = 1.f - 2.f / (ex + 1.f);
        p = fmaf(th, wfv[nf], p);
      }
      p += __shfl_xor(p, 1); p += __shfl_xor(p, 2);
      p += __shfl_xor(p, 4); p += __shfl_xor(p, 8);
      if (arow == 0) sc_part[mf * 16 + akg * 4 + r][wn] = p;
    }
  }
  __syncthreads();

  if (t < BM) {
    float s = sc_part[t][0] + sc_part[t][1] + sc_part[t][2] + sc_part[t][3];
    raw_scores[(size_t)b * LL + l0 + t] = s;
    float m = s;
#pragma unroll
    for (int off = 1; off < 64; off <<= 1) m = fmaxf(m, __shfl_xor(m, off));
    float w = __expf(s - m);
    weight[t] = w;
    float ss = w;
#pragma unroll
    for (int off = 1; off < 64; off <<= 1) ss += __shfl_xor(ss, off);
    if (t == 0) {
      ws_ms[(b * NCH + chunk) * 2]     = m;
      ws_ms[(b * NCH + chunk) * 2 + 1] = ss;
    }
  }
  __syncthreads();

  float wv[4][4];
#pragma unroll
  for (int mf = 0; mf < 4; mf++)
#pragma unroll
    for (int r = 0; r < 4; r++) wv[mf][r] = weight[mf * 16 + akg * 4 + r];
#pragma unroll
  for (int nf = 0; nf < 8; nf++) {
    float cp = 0.f;
#pragma unroll
    for (int mf = 0; mf < 4; mf++)
#pragma unroll
      for (int r = 0; r < 4; r++) cp = fmaf(wv[mf][r], acc[mf][nf][r], cp);
    cp += __shfl_xor(cp, 16);
    cp += __shfl_xor(cp, 32);
    if (lane < 16)
      ws_o[((size_t)b * NCH + chunk) * AD + wn * 128 + nf * 16 + lane] = cp;
  }
}

// ---------------- kernel 2: finalize (256 blocks; b x quarter decomposition) ----
__global__ __launch_bounds__(256) void finalize_kernel(
    const float* __restrict__ ws_ms, const float* __restrict__ ws_o,
    float* __restrict__ out0, float* __restrict__ outS) {
  const int blk = blockIdx.x, t = threadIdx.x;
  const int b = blk >> 2, q = blk & 3;
  float M = -1e30f;
  float ms[NCH], ss[NCH];
#pragma unroll
  for (int i = 0; i < NCH; i++) {
    ms[i] = ws_ms[(b * NCH + i) * 2];
    ss[i] = ws_ms[(b * NCH + i) * 2 + 1];
    M = fmaxf(M, ms[i]);
  }
  float S = 0.f, w[NCH];
#pragma unroll
  for (int i = 0; i < NCH; i++) { w[i] = __expf(ms[i] - M); S = fmaf(ss[i], w[i], S); }
  const float invS = 1.f / S;
  if (t < 128) {
    const int c = q * 128 + t;
    float a = 0.f;
#pragma unroll
    for (int i = 0; i < NCH; i++) a = fmaf(ws_o[((size_t)b * NCH + i) * AD + c], w[i], a);
    out0[b * AD + c] = a * invS;
  }
#pragma unroll
  for (int j = 0; j < 2; j++) {
    const int l = q * 512 + j * 256 + t;
    float r = outS[(size_t)b * LL + l];
    outS[(size_t)b * LL + l] = __expf(r - M) * invS;
  }
}

extern "C" void kernel_launch(void* const* d_in, const int* in_sizes, int n_in,
                              void* d_out, int out_size, void* d_ws, size_t ws_size,
                              hipStream_t stream) {
  const float* sem    = (const float*)d_in[0];
  const float* dec    = (const float*)d_in[1];
  const float* W_enc  = (const float*)d_in[2];
  const float* b_enc  = (const float*)d_in[3];
  const float* W_dec  = (const float*)d_in[4];
  const float* b_dec  = (const float*)d_in[5];
  const float* W_full = (const float*)d_in[6];
  // d_in[7] = b_full: constant shift, cancels in softmax.

  float* out0 = (float*)d_out;            // att_output [64][512]
  float* outS = out0 + BB * AD;           // att_scores [64][2048]

  char* ws = (char*)d_ws;
  unsigned short* Wb = (unsigned short*)ws;                          // 1 MB bf16 packed W_enc
  float* dpw   = (float*)(ws + (1 << 20));                           // 128 KB dec_proj+b_dec
  float* ws_ms = (float*)(ws + (1 << 20) + (128 << 10));             // 16 KB (m,s) per chunk
  float* ws_o  = (float*)(ws + (1 << 20) + (144 << 10));             // 4 MB o partials

  prep_kernel<<<144, 512, 0, stream>>>(W_enc, dec, W_dec, b_dec, Wb, dpw);
  dim3 g1(NCH, BB);
  fused_kernel<<<g1, 256, 0, stream>>>(sem, Wb, dpw, b_enc, W_full, outS, ws_ms, ws_o);
  finalize_kernel<<<BB * 4, 256, 0, stream>>>(ws_ms, ws_o, out0, outS);
}